// Round 3
// baseline (552.074 us; speedup 1.0000x reference)
//
#include <hip/hip_runtime.h>
#include <hip/hip_bf16.h>

// AttentionFusion: fused = sigmoid(<x1,w> - <x2,w>) * x1 + (1-a)*x2, alpha=[a,1-a]
// N=1e6 rows, D=64. Memory-bound: ~776 MB traffic -> ~123 us roofline @6.3 TB/s.
// Layout: 16 lanes per row, one float4 per lane (16B/lane coalesced).

__global__ __launch_bounds__(256) void attn_fuse_kernel(
    const float* __restrict__ x1,
    const float* __restrict__ x2,
    const float* __restrict__ w,
    float* __restrict__ fused,
    float* __restrict__ alpha,
    int n)
{
    const int tid = blockIdx.x * blockDim.x + threadIdx.x;
    const int row = tid >> 4;      // 16 threads per row (D=64 / 4 floats per lane)
    const int c4  = tid & 15;      // which float4 chunk of the row
    if (row >= n) return;

    const float4* x1v = reinterpret_cast<const float4*>(x1) + (size_t)row * 16 + c4;
    const float4* x2v = reinterpret_cast<const float4*>(x2) + (size_t)row * 16 + c4;
    const float4  wv  = reinterpret_cast<const float4*>(w)[c4];

    const float4 a = *x1v;
    const float4 b = *x2v;

    float s1 = a.x * wv.x + a.y * wv.y + a.z * wv.z + a.w * wv.w;
    float s2 = b.x * wv.x + b.y * wv.y + b.z * wv.z + b.w * wv.w;

    // butterfly reduce across the 16 lanes of this row
    #pragma unroll
    for (int m = 8; m >= 1; m >>= 1) {
        s1 += __shfl_xor(s1, m, 16);
        s2 += __shfl_xor(s2, m, 16);
    }

    const float d  = s1 - s2;
    float a1 = 1.0f / (1.0f + expf(-d));   // sigmoid; full-precision expf (VALU slack is huge)
    a1 = fminf(fmaxf(a1, 0.0f), 1.0f);
    const float a2 = 1.0f - a1;

    float4 o;
    o.x = a1 * a.x + a2 * b.x;
    o.y = a1 * a.y + a2 * b.y;
    o.z = a1 * a.z + a2 * b.z;
    o.w = a1 * a.w + a2 * b.w;
    reinterpret_cast<float4*>(fused)[(size_t)row * 16 + c4] = o;

    if (c4 == 0) {
        float2 al;
        al.x = a1;
        al.y = a2;
        reinterpret_cast<float2*>(alpha)[row] = al;
    }
}

extern "C" void kernel_launch(void* const* d_in, const int* in_sizes, int n_in,
                              void* d_out, int out_size, void* d_ws, size_t ws_size,
                              hipStream_t stream) {
    const float* x1 = (const float*)d_in[0];
    const float* x2 = (const float*)d_in[1];
    const float* w  = (const float*)d_in[2];

    const int n = in_sizes[0] / 64;           // N rows
    float* fused = (float*)d_out;             // N*64 floats
    float* alpha = (float*)d_out + (size_t)n * 64;  // N*2 floats

    const int threads = 256;                  // 16 rows per block
    const int rows_per_block = threads / 16;
    const int grid = (n + rows_per_block - 1) / rows_per_block;

    attn_fuse_kernel<<<grid, threads, 0, stream>>>(x1, x2, w, fused, alpha, n);
}